// Round 14
// baseline (185.062 us; speedup 1.0000x reference)
//
#include <hip/hip_runtime.h>

// CapsuleLayer: B=64, L=512, D=1024, C=32, O=64, 3 routing iters.
// u_hat never materialized:
//   dots[b,l,c] = in[b,l,:]@w_v[b,c,:] + bias_v[b,c]   (w_v[b,c,d] = sum_o fc_w[d,cO+o] v[b,c,o])
//   s_j[b,c,:]  = x_c[b,c,:]@fc_w[:,c,:] + csum[b,c]*fc_b[c,:]   (x_c = sum_l c_w * in)
// All contractions via mfma_f32_16x16x32_bf16. Single bf16 input copy
// in_bf[b][l][d]. k_ctr: fully-sequential streaming (1024 blocks x 128 KB).
// k_route2: K split across wave pairs (LDS-reduced) -> 4 waves/SIMD.
// k_xc_m: 64-d tiles (1024 blocks, 9.2 KB LDS -> 4 waves/SIMD), LDS l-pair
// transpose staging + T14 async-stage pipeline.

namespace {
constexpr int Bn = 64, Ln = 512, Dn = 1024, Cn = 32, On = 64, COn = Cn * On;
}

typedef float f32x4 __attribute__((ext_vector_type(4)));
typedef short bf16x8 __attribute__((ext_vector_type(8)));

static __device__ __forceinline__ unsigned f2bf(float f) {
    unsigned u = __float_as_uint(f);
    u += 0x7fff + ((u >> 16) & 1);   // RNE
    return u >> 16;
}

// ------------------------------------------------------------ conv ----------
// grid (16 lc, 64 b): block streams 32 complete rows (128 KB contiguous).
// Wave w covers d in [w*256, w*256+256); lane owns one float4 column.
__global__ __launch_bounds__(256) void k_ctr(const float* __restrict__ in,
                                             short* __restrict__ in_bf,
                                             float* __restrict__ rs_p) {
    int lc = blockIdx.x, b = blockIdx.y;
    int t = threadIdx.x, w = t >> 6, lane = t & 63;
    int l0 = lc * 32;
    int d0 = w * 256 + lane * 4;
    const float* src = in + ((size_t)b * Ln + l0) * Dn + d0;
    short* dst = in_bf + ((size_t)b * Ln + l0) * Dn + d0;
    float4 s4 = make_float4(0.f, 0.f, 0.f, 0.f);
#pragma unroll 8
    for (int r = 0; r < 32; ++r) {
        float4 x = *(const float4*)(src + (size_t)r * Dn);
        s4.x += x.x; s4.y += x.y; s4.z += x.z; s4.w += x.w;
        unsigned lo = f2bf(x.x) | (f2bf(x.y) << 16);
        unsigned hi = f2bf(x.z) | (f2bf(x.w) << 16);
        *(uint2*)(dst + (size_t)r * Dn) = make_uint2(lo, hi);
    }
    *(float4*)(rs_p + ((size_t)b * 16 + lc) * Dn + d0) = s4;
}

// -------------------------------------------------------- wprep + rsred -----
// blocks [0,128): fc_w fp32 [d][co] -> fc_wT bf16 [co][d] + fc_wb bf16 [d][co]
// blocks [128,384): rsred — rs_p partials (16) -> rs_bf (/32, bf16)
__global__ __launch_bounds__(256) void k_prep2(const float* __restrict__ fc_w,
                                               short* __restrict__ fc_wT,
                                               short* __restrict__ fc_wb,
                                               const float* __restrict__ rs_p,
                                               unsigned short* __restrict__ rs_bf) {
    __shared__ short tr[64 * 260];      // used by wprep blocks only
    int t = threadIdx.x;
    if (blockIdx.x < 128) {
        int id = blockIdx.x;
        int d0 = (id & 15) * 64;
        int co0 = (id >> 4) * 256;
        int grp = t >> 6, cq = t & 63;
#pragma unroll
        for (int i = 0; i < 16; ++i) {
            int row = grp + 4 * i;
            float4 x = *(const float4*)(fc_w + (size_t)(d0 + row) * COn + co0 + cq * 4);
            short4 s4 = make_short4((short)f2bf(x.x), (short)f2bf(x.y),
                                    (short)f2bf(x.z), (short)f2bf(x.w));
            *(short4*)(&tr[row * 260 + cq * 4]) = s4;
            *(short4*)(fc_wb + (size_t)(d0 + row) * COn + co0 + cq * 4) = s4;
        }
        __syncthreads();
#pragma unroll
        for (int i = 0; i < 8; ++i) {
            int idx = t + 256 * i;
            int corow = idx >> 3, slot = idx & 7;
            bf16x8 v;
#pragma unroll
            for (int j = 0; j < 8; ++j) v[j] = tr[(slot * 8 + j) * 260 + corow];
            *(bf16x8*)(fc_wT + (size_t)(co0 + corow) * Dn + d0 + slot * 8) = v;
        }
    } else {
        int id = blockIdx.x - 128;      // 0..255
        int b = id >> 2, dq = id & 3;
        int d = dq * 256 + t;
        float s = 0.f;
#pragma unroll
        for (int lc = 0; lc < 16; ++lc) s += rs_p[((size_t)b * 16 + lc) * Dn + d];
        rs_bf[b * Dn + d] = (unsigned short)f2bf(s * (1.0f / 32.0f));
    }
}

// ------------------------------------------------------- s -> squash -> v ---
// Per-(btile,c) MFMA GEMM: one wave computes S[16 b][64 o]. Grid (4, 32).
__global__ __launch_bounds__(64) void k_sv3(const short* __restrict__ xA,
                                            const float* __restrict__ csum_p,
                                            const short* __restrict__ fc_wT,
                                            const float* __restrict__ fc_b,
                                            short* __restrict__ v_bf,
                                            float* __restrict__ fout,
                                            float* __restrict__ bias_v,
                                            int mode0) {
    int w = blockIdx.x;                 // b-tile 0..3
    int c = blockIdx.y;
    int lane = threadIdx.x;             // 0..63
    int l15 = lane & 15, lg = lane >> 4;
    const short* A = mode0 ? xA : (xA + (size_t)c * Bn * Dn);   // [b][d]
    const short* Bw = fc_wT + (size_t)c * On * Dn;              // [o][d]
    f32x4 acc[4];
#pragma unroll
    for (int i = 0; i < 4; ++i) acc[i] = {0.f, 0.f, 0.f, 0.f};
#pragma unroll 4
    for (int ks = 0; ks < 32; ++ks) {
        int koff = ks * 32 + lg * 8;
        bf16x8 a = *(const bf16x8*)(A + (size_t)(w * 16 + l15) * Dn + koff);
#pragma unroll
        for (int dt = 0; dt < 4; ++dt) {
            bf16x8 bbf = *(const bf16x8*)(Bw + (size_t)(dt * 16 + l15) * Dn + koff);
            acc[dt] = __builtin_amdgcn_mfma_f32_16x16x32_bf16(a, bbf, acc[dt], 0, 0, 0);
        }
    }
    float fb[4];
#pragma unroll
    for (int dt = 0; dt < 4; ++dt) fb[dt] = fc_b[c * On + dt * 16 + l15];
#pragma unroll
    for (int r = 0; r < 4; ++r) {
        int brow = w * 16 + lg * 4 + r;
        float cs;
        if (mode0) {
            cs = 16.0f;
        } else {
            cs = 0.f;
#pragma unroll
            for (int lt = 0; lt < 16; ++lt) cs += csum_p[((size_t)lt * Bn + brow) * Cn + c];
        }
        float s0 = acc[0][r] + cs * fb[0];
        float s1 = acc[1][r] + cs * fb[1];
        float s2 = acc[2][r] + cs * fb[2];
        float s3 = acc[3][r] + cs * fb[3];
        float sq = s0 * s0 + s1 * s1 + s2 * s2 + s3 * s3;
        sq += __shfl_xor(sq, 1, 64); sq += __shfl_xor(sq, 2, 64);
        sq += __shfl_xor(sq, 4, 64); sq += __shfl_xor(sq, 8, 64);
        float scale = sq / (1.0f + sq) * rsqrtf(sq + 1e-8f);
        float v0 = scale * s0, v1 = scale * s1, v2 = scale * s2, v3 = scale * s3;
        size_t vo = ((size_t)brow * Cn + c) * On;
        v_bf[vo + 0 * 16 + l15] = (short)f2bf(v0);
        v_bf[vo + 1 * 16 + l15] = (short)f2bf(v1);
        v_bf[vo + 2 * 16 + l15] = (short)f2bf(v2);
        v_bf[vo + 3 * 16 + l15] = (short)f2bf(v3);
        if (fout) {
            fout[vo + 0 * 16 + l15] = v0;
            fout[vo + 1 * 16 + l15] = v1;
            fout[vo + 2 * 16 + l15] = v2;
            fout[vo + 3 * 16 + l15] = v3;
        }
        float bv = fb[0] * v0 + fb[1] * v1 + fb[2] * v2 + fb[3] * v3;
        bv += __shfl_xor(bv, 1, 64); bv += __shfl_xor(bv, 2, 64);
        bv += __shfl_xor(bv, 4, 64); bv += __shfl_xor(bv, 8, 64);
        if (l15 == 0) bias_v[brow * Cn + c] = bv;
    }
}

// ------------------------------------------- w_v via MFMA (contract o=64) ---
// grid (4 dslab, 32 c), 256 thr / 4 waves; wave: 64 d x 64 b, K=64.
__global__ __launch_bounds__(256) void k_wv_m(const short* __restrict__ fc_wb,
                                              const short* __restrict__ v_bf,
                                              short* __restrict__ w_vb) {
    int dsl = blockIdx.x, c = blockIdx.y;
    int t = threadIdx.x, w = t >> 6, lane = t & 63;
    int l15 = lane & 15, lg = lane >> 4;
    int dbase = dsl * 256 + w * 64;
    f32x4 acc[4][4];
#pragma unroll
    for (int i = 0; i < 4; ++i)
#pragma unroll
        for (int j = 0; j < 4; ++j) acc[i][j] = {0.f, 0.f, 0.f, 0.f};
#pragma unroll
    for (int ks = 0; ks < 2; ++ks) {
        int o = ks * 32 + lg * 8;
        bf16x8 bfr[4];
#pragma unroll
        for (int nt = 0; nt < 4; ++nt)
            bfr[nt] = *(const bf16x8*)(v_bf + ((size_t)(nt * 16 + l15) * Cn + c) * On + o);
#pragma unroll
        for (int mt = 0; mt < 4; ++mt) {
            bf16x8 a = *(const bf16x8*)(fc_wb + (size_t)(dbase + mt * 16 + l15) * COn + c * On + o);
#pragma unroll
            for (int nt = 0; nt < 4; ++nt)
                acc[mt][nt] = __builtin_amdgcn_mfma_f32_16x16x32_bf16(a, bfr[nt], acc[mt][nt], 0, 0, 0);
        }
    }
#pragma unroll
    for (int mt = 0; mt < 4; ++mt)
#pragma unroll
        for (int nt = 0; nt < 4; ++nt) {
            int bb = nt * 16 + l15;
            int d = dbase + mt * 16 + lg * 4;
            *(short4*)(w_vb + ((size_t)bb * Cn + c) * Dn + d) =
                make_short4((short)f2bf(acc[mt][nt][0]), (short)f2bf(acc[mt][nt][1]),
                            (short)f2bf(acc[mt][nt][2]), (short)f2bf(acc[mt][nt][3]));
        }
}

// ------------------------------- dots -> b_ij update -> softmax -> c_wT -----
// K-split: grid (16 lt2, 64 b), 4 waves = 2 l-groups x 2 K-halves. Each wave
// does K=512; partners LDS-reduce. 1024 blocks -> 4 waves/SIMD.
__global__ __launch_bounds__(256) void k_route2(const short* __restrict__ in_bf,
                                                const short* __restrict__ w_v,
                                                const float* __restrict__ bias_v,
                                                float* __restrict__ b_ij,
                                                short* __restrict__ c_wT,
                                                float* __restrict__ csum_p,
                                                int first, int last) {
    __shared__ float red[2][8][64];     // [lgrp][acc j][lane]
    __shared__ short cw_sh[Cn * 40];    // [c][32 l + pad]
    __shared__ float cs_sh[2][Cn];
    int lt2 = blockIdx.x, b = blockIdx.y;
    int t = threadIdx.x, w = t >> 6, lane = t & 63;
    int lgrp = w >> 1, kh = w & 1;
    int l15 = lane & 15, lg = lane >> 4;
    int l0 = lt2 * 32 + lgrp * 16;
    f32x4 acc0 = {0.f, 0.f, 0.f, 0.f}, acc1 = {0.f, 0.f, 0.f, 0.f};
    const short* Ap = in_bf + ((size_t)b * Ln + l0 + l15) * Dn + kh * 512;
    const short* Bp = w_v + (size_t)b * Cn * Dn + kh * 512;
#pragma unroll 4
    for (int ks = 0; ks < 16; ++ks) {
        int koff = ks * 32 + lg * 8;
        bf16x8 a = *(const bf16x8*)(Ap + koff);
        bf16x8 b0 = *(const bf16x8*)(Bp + (size_t)l15 * Dn + koff);
        bf16x8 b1 = *(const bf16x8*)(Bp + (size_t)(l15 + 16) * Dn + koff);
        acc0 = __builtin_amdgcn_mfma_f32_16x16x32_bf16(a, b0, acc0, 0, 0, 0);
        acc1 = __builtin_amdgcn_mfma_f32_16x16x32_bf16(a, b1, acc1, 0, 0, 0);
    }
    if (kh == 1) {
#pragma unroll
        for (int j = 0; j < 4; ++j) {
            red[lgrp][j][lane] = acc0[j];
            red[lgrp][4 + j][lane] = acc1[j];
        }
    }
    __syncthreads();
    if (kh == 0) {
#pragma unroll
        for (int j = 0; j < 4; ++j) {
            acc0[j] += red[lgrp][j][lane];
            acc1[j] += red[lgrp][4 + j][lane];
        }
        float bv0 = bias_v[b * Cn + l15];
        float bv1 = bias_v[b * Cn + l15 + 16];
        float csa0 = 0.f, csa1 = 0.f;
#pragma unroll
        for (int r = 0; r < 4; ++r) {
            int lrow = l0 + lg * 4 + r;
            size_t boff = ((size_t)b * Ln + lrow) * Cn;
            float d0 = acc0[r] + bv0, d1 = acc1[r] + bv1;
            if (!first) { d0 += b_ij[boff + l15]; d1 += b_ij[boff + l15 + 16]; }
            if (!last) {
                b_ij[boff + l15] = d0;
                b_ij[boff + l15 + 16] = d1;
            }
            float m = fmaxf(d0, d1);
            m = fmaxf(m, __shfl_xor(m, 1, 64)); m = fmaxf(m, __shfl_xor(m, 2, 64));
            m = fmaxf(m, __shfl_xor(m, 4, 64)); m = fmaxf(m, __shfl_xor(m, 8, 64));
            float e0 = __expf(d0 - m), e1 = __expf(d1 - m);
            float sm = e0 + e1;
            sm += __shfl_xor(sm, 1, 64); sm += __shfl_xor(sm, 2, 64);
            sm += __shfl_xor(sm, 4, 64); sm += __shfl_xor(sm, 8, 64);
            float inv = 1.0f / sm;
            float cw0 = e0 * inv, cw1 = e1 * inv;
            csa0 += cw0; csa1 += cw1;
            int ll = lgrp * 16 + lg * 4 + r;
            cw_sh[l15 * 40 + ll] = (short)f2bf(cw0);
            cw_sh[(l15 + 16) * 40 + ll] = (short)f2bf(cw1);
        }
        csa0 += __shfl_xor(csa0, 16, 64); csa0 += __shfl_xor(csa0, 32, 64);
        csa1 += __shfl_xor(csa1, 16, 64); csa1 += __shfl_xor(csa1, 32, 64);
        if (lg == 0) { cs_sh[lgrp][l15] = csa0; cs_sh[lgrp][l15 + 16] = csa1; }
    }
    __syncthreads();
    if (t < Cn) {
        float s = cs_sh[0][t] + cs_sh[1][t];
        csum_p[((size_t)lt2 * Bn + b) * Cn + t] = s;
    }
    if (t < 128) {
        int cc = t >> 2, slot = t & 3;
        bf16x8 vv;
#pragma unroll
        for (int j = 0; j < 8; ++j) vv[j] = cw_sh[cc * 40 + slot * 8 + j];
        *(bf16x8*)(c_wT + ((size_t)b * Cn + cc) * Ln + lt2 * 32 + slot * 8) = vv;
    }
}

// ----------------------------------------- x_cb[c][b][d] = c_w^T @ in -------
// grid (16 dt, 64 b), 256 thr / 4 waves; 64-d tiles, 9.2 KB LDS ->
// 4 blocks/CU = 4 waves/SIMD. T14 async-stage pipeline; LDS [64 d][36 u32]
// l-pair pack, XOR-chunk swizzle (same involution as before).
__global__ __launch_bounds__(256) void k_xc_m(const short* __restrict__ in_bf,
                                              const short* __restrict__ c_wT,
                                              short* __restrict__ x_cb) {
    __shared__ unsigned tile[64 * 36];   // 9216 B
    int dt = blockIdx.x, b = blockIdx.y;
    int t = threadIdx.x, w = t >> 6, lane = t & 63;
    int l15 = lane & 15, lg = lane >> 4;
    f32x4 acc[2];
#pragma unroll
    for (int h = 0; h < 2; ++h) acc[h] = {0.f, 0.f, 0.f, 0.f};
    const short* A = c_wT + (size_t)b * Cn * Ln;   // [c][l]

    // staging ownership: oct = d-octet (0..7), lp = l-pair (0..31)
    int oct = t & 7, lp = t >> 3;
    const short* gbase = in_bf + (size_t)b * Ln * Dn + dt * 64 + oct * 8;
    int col = lp ^ (oct << 2);
    unsigned* trow = &tile[(oct * 8) * 36];

    bf16x8 ra0, ra1;                        // staged in_bf micro-rows
    bf16x8 a0c[2], a1c[2], a0n[2], a1n[2];  // A-fragments, cur/next

#define XC_LOADG(LC)                                                          \
    {                                                                         \
        const short* sA = gbase + (size_t)((LC) * 64 + 2 * lp) * Dn;          \
        ra0 = *(const bf16x8*)sA; ra1 = *(const bf16x8*)(sA + Dn);            \
    }
#define XC_LOADA(LC, D0, D1)                                                  \
    _Pragma("unroll")                                                         \
    for (int ks = 0; ks < 2; ++ks) {                                          \
        int off = (LC) * 64 + ks * 32 + lg * 8;                               \
        D0[ks] = *(const bf16x8*)(A + (size_t)l15 * Ln + off);                \
        D1[ks] = *(const bf16x8*)(A + (size_t)(l15 + 16) * Ln + off);         \
    }

    XC_LOADG(0);
    XC_LOADA(0, a0c, a1c);

    for (int lc = 0; lc < 8; ++lc) {
#pragma unroll
        for (int k = 0; k < 8; ++k) {
            trow[k * 36 + col] = (unsigned)(unsigned short)ra0[k] |
                                 ((unsigned)(unsigned short)ra1[k] << 16);
        }
        __syncthreads();
        if (lc < 7) {
            XC_LOADG(lc + 1);
            XC_LOADA(lc + 1, a0n, a1n);
        }
#pragma unroll
        for (int ks = 0; ks < 2; ++ks) {
            int q = ks * 4 + lg;               // u32 chunk index
            int dloc = w * 16 + l15;
            int qs = q ^ ((dloc >> 3) & 7);
            bf16x8 bb = *(const bf16x8*)&tile[dloc * 36 + qs * 4];
            acc[0] = __builtin_amdgcn_mfma_f32_16x16x32_bf16(a0c[ks], bb, acc[0], 0, 0, 0);
            acc[1] = __builtin_amdgcn_mfma_f32_16x16x32_bf16(a1c[ks], bb, acc[1], 0, 0, 0);
        }
        __syncthreads();
        if (lc < 7) {
#pragma unroll
            for (int ks = 0; ks < 2; ++ks) { a0c[ks] = a0n[ks]; a1c[ks] = a1n[ks]; }
        }
    }
#undef XC_LOADG
#undef XC_LOADA
#pragma unroll
    for (int h = 0; h < 2; ++h)
#pragma unroll
        for (int r = 0; r < 4; ++r) {
            int c = 16 * h + lg * 4 + r;
            int d = dt * 64 + w * 16 + l15;
            x_cb[((size_t)c * Bn + b) * Dn + d] = (short)f2bf(acc[h][r]);
        }
}

// ---------------------------------------------------------------------------
extern "C" void kernel_launch(void* const* d_in, const int* in_sizes, int n_in,
                              void* d_out, int out_size, void* d_ws, size_t ws_size,
                              hipStream_t stream) {
    const float* in   = (const float*)d_in[0];
    const float* fc_w = (const float*)d_in[1];
    const float* fc_b = (const float*)d_in[2];
    float* out = (float*)d_out;

    char* p = (char*)d_ws;
    auto alloc = [&](size_t bytes) -> char* {
        char* r = p;
        p += (bytes + 255) & ~(size_t)255;
        return r;
    };
    short* in_bf  = (short*)alloc((size_t)Bn * Ln * Dn * 2);   // 64 MB
    short* fc_wT  = (short*)alloc((size_t)COn * Dn * 2);       // 4 MB
    short* fc_wb  = (short*)alloc((size_t)COn * Dn * 2);       // 4 MB
    short* w_vb   = (short*)alloc((size_t)Bn * Cn * Dn * 2);   // 4 MB
    short* c_wT   = (short*)alloc((size_t)Bn * Cn * Ln * 2);   // 2 MB
    short* x_cb   = (short*)alloc((size_t)Cn * Bn * Dn * 2);   // 4 MB
    short* v_bf   = (short*)alloc((size_t)Bn * Cn * On * 2);   // 256 KB
    float* rs_p   = (float*)alloc((size_t)Bn * 16 * Dn * 4);   // 4 MB
    unsigned short* rs_bf = (unsigned short*)alloc((size_t)Bn * Dn * 2);
    float* b_ij   = (float*)alloc((size_t)Bn * Ln * Cn * 4);   // 4 MB
    float* bias_v = (float*)alloc((size_t)Bn * Cn * 4);
    float* csum_p = (float*)alloc((size_t)16 * Bn * Cn * 4);

    k_ctr<<<dim3(16, Bn), 256, 0, stream>>>(in, in_bf, rs_p);
    k_prep2<<<384, 256, 0, stream>>>(fc_w, fc_wT, fc_wb, rs_p, rs_bf);
    k_sv3<<<dim3(4, Cn), 64, 0, stream>>>((const short*)rs_bf, csum_p, fc_wT,
                                          fc_b, v_bf, nullptr, bias_v, 1);
    for (int it = 1; it <= 2; ++it) {
        k_wv_m<<<dim3(4, Cn), 256, 0, stream>>>(fc_wb, v_bf, w_vb);
        k_route2<<<dim3(16, Bn), 256, 0, stream>>>(in_bf, w_vb, bias_v, b_ij,
                                                   c_wT, csum_p,
                                                   (it == 1) ? 1 : 0,
                                                   (it == 2) ? 1 : 0);
        k_xc_m<<<dim3(16, Bn), 256, 0, stream>>>(in_bf, c_wT, x_cb);
        k_sv3<<<dim3(4, Cn), 64, 0, stream>>>(x_cb, csum_p, fc_wT, fc_b,
                                              v_bf, (it == 2) ? out : nullptr,
                                              bias_v, 0);
    }
}

// Round 16
// 177.216 us; speedup vs baseline: 1.0443x; 1.0443x over previous
//
#include <hip/hip_runtime.h>

// CapsuleLayer: B=64, L=512, D=1024, C=32, O=64, 3 routing iters.
// u_hat never materialized:
//   dots[b,l,c] = in[b,l,:]@w_v[b,c,:] + bias_v[b,c]   (w_v[b,c,d] = sum_o fc_w[d,cO+o] v[b,c,o])
//   s_j[b,c,:]  = x_c[b,c,:]@fc_w[:,c,:] + csum[b,c]*fc_b[c,:]   (x_c = sum_l c_w * in)
// All contractions via mfma_f32_16x16x32_bf16. Single bf16 input copy
// in_bf[b][l][d]. k_ctr: fully-sequential streaming, NT input loads
// (ext-vector type: __builtin_nontemporal_load rejects HIP_vector_type).
// k_route2: K split across wave pairs (LDS-reduced) -> 4 waves/SIMD.
// k_xc_m: 128-d tiles (R13-proven), LDS l-pair transpose staging + T14
// async-stage pipeline.

namespace {
constexpr int Bn = 64, Ln = 512, Dn = 1024, Cn = 32, On = 64, COn = Cn * On;
}

typedef float f32x4 __attribute__((ext_vector_type(4)));
typedef short bf16x8 __attribute__((ext_vector_type(8)));

static __device__ __forceinline__ unsigned f2bf(float f) {
    unsigned u = __float_as_uint(f);
    u += 0x7fff + ((u >> 16) & 1);   // RNE
    return u >> 16;
}

// ------------------------------------------------------------ conv ----------
// grid (16 lc, 64 b): block streams 32 complete rows (128 KB contiguous).
// Wave w covers d in [w*256, w*256+256); lane owns one float4 column.
// Input read once -> non-temporal load hint (keep L3 for in_bf).
__global__ __launch_bounds__(256) void k_ctr(const float* __restrict__ in,
                                             short* __restrict__ in_bf,
                                             float* __restrict__ rs_p) {
    int lc = blockIdx.x, b = blockIdx.y;
    int t = threadIdx.x, w = t >> 6, lane = t & 63;
    int l0 = lc * 32;
    int d0 = w * 256 + lane * 4;
    const f32x4* src = (const f32x4*)(in + ((size_t)b * Ln + l0) * Dn + d0);
    short* dst = in_bf + ((size_t)b * Ln + l0) * Dn + d0;
    float sx = 0.f, sy = 0.f, sz = 0.f, sw = 0.f;
#pragma unroll 8
    for (int r = 0; r < 32; ++r) {
        f32x4 x = __builtin_nontemporal_load(src + (size_t)r * (Dn / 4));
        sx += x[0]; sy += x[1]; sz += x[2]; sw += x[3];
        unsigned lo = f2bf(x[0]) | (f2bf(x[1]) << 16);
        unsigned hi = f2bf(x[2]) | (f2bf(x[3]) << 16);
        *(uint2*)(dst + (size_t)r * Dn) = make_uint2(lo, hi);
    }
    *(float4*)(rs_p + ((size_t)b * 16 + lc) * Dn + d0) =
        make_float4(sx, sy, sz, sw);
}

// -------------------------------------------------------- wprep + rsred -----
// blocks [0,128): fc_w fp32 [d][co] -> fc_wT bf16 [co][d] + fc_wb bf16 [d][co]
// blocks [128,384): rsred — rs_p partials (16) -> rs_bf (/32, bf16)
__global__ __launch_bounds__(256) void k_prep2(const float* __restrict__ fc_w,
                                               short* __restrict__ fc_wT,
                                               short* __restrict__ fc_wb,
                                               const float* __restrict__ rs_p,
                                               unsigned short* __restrict__ rs_bf) {
    __shared__ short tr[64 * 260];      // used by wprep blocks only
    int t = threadIdx.x;
    if (blockIdx.x < 128) {
        int id = blockIdx.x;
        int d0 = (id & 15) * 64;
        int co0 = (id >> 4) * 256;
        int grp = t >> 6, cq = t & 63;
#pragma unroll
        for (int i = 0; i < 16; ++i) {
            int row = grp + 4 * i;
            float4 x = *(const float4*)(fc_w + (size_t)(d0 + row) * COn + co0 + cq * 4);
            short4 s4 = make_short4((short)f2bf(x.x), (short)f2bf(x.y),
                                    (short)f2bf(x.z), (short)f2bf(x.w));
            *(short4*)(&tr[row * 260 + cq * 4]) = s4;
            *(short4*)(fc_wb + (size_t)(d0 + row) * COn + co0 + cq * 4) = s4;
        }
        __syncthreads();
#pragma unroll
        for (int i = 0; i < 8; ++i) {
            int idx = t + 256 * i;
            int corow = idx >> 3, slot = idx & 7;
            bf16x8 v;
#pragma unroll
            for (int j = 0; j < 8; ++j) v[j] = tr[(slot * 8 + j) * 260 + corow];
            *(bf16x8*)(fc_wT + (size_t)(co0 + corow) * Dn + d0 + slot * 8) = v;
        }
    } else {
        int id = blockIdx.x - 128;      // 0..255
        int b = id >> 2, dq = id & 3;
        int d = dq * 256 + t;
        float s = 0.f;
#pragma unroll
        for (int lc = 0; lc < 16; ++lc) s += rs_p[((size_t)b * 16 + lc) * Dn + d];
        rs_bf[b * Dn + d] = (unsigned short)f2bf(s * (1.0f / 32.0f));
    }
}

// ------------------------------------------------------- s -> squash -> v ---
// Per-(btile,c) MFMA GEMM: one wave computes S[16 b][64 o]. Grid (4, 32).
__global__ __launch_bounds__(64) void k_sv3(const short* __restrict__ xA,
                                            const float* __restrict__ csum_p,
                                            const short* __restrict__ fc_wT,
                                            const float* __restrict__ fc_b,
                                            short* __restrict__ v_bf,
                                            float* __restrict__ fout,
                                            float* __restrict__ bias_v,
                                            int mode0) {
    int w = blockIdx.x;                 // b-tile 0..3
    int c = blockIdx.y;
    int lane = threadIdx.x;             // 0..63
    int l15 = lane & 15, lg = lane >> 4;
    const short* A = mode0 ? xA : (xA + (size_t)c * Bn * Dn);   // [b][d]
    const short* Bw = fc_wT + (size_t)c * On * Dn;              // [o][d]
    f32x4 acc[4];
#pragma unroll
    for (int i = 0; i < 4; ++i) acc[i] = {0.f, 0.f, 0.f, 0.f};
#pragma unroll 4
    for (int ks = 0; ks < 32; ++ks) {
        int koff = ks * 32 + lg * 8;
        bf16x8 a = *(const bf16x8*)(A + (size_t)(w * 16 + l15) * Dn + koff);
#pragma unroll
        for (int dt = 0; dt < 4; ++dt) {
            bf16x8 bbf = *(const bf16x8*)(Bw + (size_t)(dt * 16 + l15) * Dn + koff);
            acc[dt] = __builtin_amdgcn_mfma_f32_16x16x32_bf16(a, bbf, acc[dt], 0, 0, 0);
        }
    }
    float fb[4];
#pragma unroll
    for (int dt = 0; dt < 4; ++dt) fb[dt] = fc_b[c * On + dt * 16 + l15];
#pragma unroll
    for (int r = 0; r < 4; ++r) {
        int brow = w * 16 + lg * 4 + r;
        float cs;
        if (mode0) {
            cs = 16.0f;
        } else {
            cs = 0.f;
#pragma unroll
            for (int lt = 0; lt < 16; ++lt) cs += csum_p[((size_t)lt * Bn + brow) * Cn + c];
        }
        float s0 = acc[0][r] + cs * fb[0];
        float s1 = acc[1][r] + cs * fb[1];
        float s2 = acc[2][r] + cs * fb[2];
        float s3 = acc[3][r] + cs * fb[3];
        float sq = s0 * s0 + s1 * s1 + s2 * s2 + s3 * s3;
        sq += __shfl_xor(sq, 1, 64); sq += __shfl_xor(sq, 2, 64);
        sq += __shfl_xor(sq, 4, 64); sq += __shfl_xor(sq, 8, 64);
        float scale = sq / (1.0f + sq) * rsqrtf(sq + 1e-8f);
        float v0 = scale * s0, v1 = scale * s1, v2 = scale * s2, v3 = scale * s3;
        size_t vo = ((size_t)brow * Cn + c) * On;
        v_bf[vo + 0 * 16 + l15] = (short)f2bf(v0);
        v_bf[vo + 1 * 16 + l15] = (short)f2bf(v1);
        v_bf[vo + 2 * 16 + l15] = (short)f2bf(v2);
        v_bf[vo + 3 * 16 + l15] = (short)f2bf(v3);
        if (fout) {
            fout[vo + 0 * 16 + l15] = v0;
            fout[vo + 1 * 16 + l15] = v1;
            fout[vo + 2 * 16 + l15] = v2;
            fout[vo + 3 * 16 + l15] = v3;
        }
        float bv = fb[0] * v0 + fb[1] * v1 + fb[2] * v2 + fb[3] * v3;
        bv += __shfl_xor(bv, 1, 64); bv += __shfl_xor(bv, 2, 64);
        bv += __shfl_xor(bv, 4, 64); bv += __shfl_xor(bv, 8, 64);
        if (l15 == 0) bias_v[brow * Cn + c] = bv;
    }
}

// ------------------------------------------- w_v via MFMA (contract o=64) ---
// grid (4 dslab, 32 c), 256 thr / 4 waves; wave: 64 d x 64 b, K=64.
__global__ __launch_bounds__(256) void k_wv_m(const short* __restrict__ fc_wb,
                                              const short* __restrict__ v_bf,
                                              short* __restrict__ w_vb) {
    int dsl = blockIdx.x, c = blockIdx.y;
    int t = threadIdx.x, w = t >> 6, lane = t & 63;
    int l15 = lane & 15, lg = lane >> 4;
    int dbase = dsl * 256 + w * 64;
    f32x4 acc[4][4];
#pragma unroll
    for (int i = 0; i < 4; ++i)
#pragma unroll
        for (int j = 0; j < 4; ++j) acc[i][j] = {0.f, 0.f, 0.f, 0.f};
#pragma unroll
    for (int ks = 0; ks < 2; ++ks) {
        int o = ks * 32 + lg * 8;
        bf16x8 bfr[4];
#pragma unroll
        for (int nt = 0; nt < 4; ++nt)
            bfr[nt] = *(const bf16x8*)(v_bf + ((size_t)(nt * 16 + l15) * Cn + c) * On + o);
#pragma unroll
        for (int mt = 0; mt < 4; ++mt) {
            bf16x8 a = *(const bf16x8*)(fc_wb + (size_t)(dbase + mt * 16 + l15) * COn + c * On + o);
#pragma unroll
            for (int nt = 0; nt < 4; ++nt)
                acc[mt][nt] = __builtin_amdgcn_mfma_f32_16x16x32_bf16(a, bfr[nt], acc[mt][nt], 0, 0, 0);
        }
    }
#pragma unroll
    for (int mt = 0; mt < 4; ++mt)
#pragma unroll
        for (int nt = 0; nt < 4; ++nt) {
            int bb = nt * 16 + l15;
            int d = dbase + mt * 16 + lg * 4;
            *(short4*)(w_vb + ((size_t)bb * Cn + c) * Dn + d) =
                make_short4((short)f2bf(acc[mt][nt][0]), (short)f2bf(acc[mt][nt][1]),
                            (short)f2bf(acc[mt][nt][2]), (short)f2bf(acc[mt][nt][3]));
        }
}

// ------------------------------- dots -> b_ij update -> softmax -> c_wT -----
// K-split: grid (16 lt2, 64 b), 4 waves = 2 l-groups x 2 K-halves. Each wave
// does K=512; partners LDS-reduce. 1024 blocks -> 4 waves/SIMD.
__global__ __launch_bounds__(256) void k_route2(const short* __restrict__ in_bf,
                                                const short* __restrict__ w_v,
                                                const float* __restrict__ bias_v,
                                                float* __restrict__ b_ij,
                                                short* __restrict__ c_wT,
                                                float* __restrict__ csum_p,
                                                int first, int last) {
    __shared__ float red[2][8][64];     // [lgrp][acc j][lane]
    __shared__ short cw_sh[Cn * 40];    // [c][32 l + pad]
    __shared__ float cs_sh[2][Cn];
    int lt2 = blockIdx.x, b = blockIdx.y;
    int t = threadIdx.x, w = t >> 6, lane = t & 63;
    int lgrp = w >> 1, kh = w & 1;
    int l15 = lane & 15, lg = lane >> 4;
    int l0 = lt2 * 32 + lgrp * 16;
    f32x4 acc0 = {0.f, 0.f, 0.f, 0.f}, acc1 = {0.f, 0.f, 0.f, 0.f};
    const short* Ap = in_bf + ((size_t)b * Ln + l0 + l15) * Dn + kh * 512;
    const short* Bp = w_v + (size_t)b * Cn * Dn + kh * 512;
#pragma unroll 4
    for (int ks = 0; ks < 16; ++ks) {
        int koff = ks * 32 + lg * 8;
        bf16x8 a = *(const bf16x8*)(Ap + koff);
        bf16x8 b0 = *(const bf16x8*)(Bp + (size_t)l15 * Dn + koff);
        bf16x8 b1 = *(const bf16x8*)(Bp + (size_t)(l15 + 16) * Dn + koff);
        acc0 = __builtin_amdgcn_mfma_f32_16x16x32_bf16(a, b0, acc0, 0, 0, 0);
        acc1 = __builtin_amdgcn_mfma_f32_16x16x32_bf16(a, b1, acc1, 0, 0, 0);
    }
    if (kh == 1) {
#pragma unroll
        for (int j = 0; j < 4; ++j) {
            red[lgrp][j][lane] = acc0[j];
            red[lgrp][4 + j][lane] = acc1[j];
        }
    }
    __syncthreads();
    if (kh == 0) {
#pragma unroll
        for (int j = 0; j < 4; ++j) {
            acc0[j] += red[lgrp][j][lane];
            acc1[j] += red[lgrp][4 + j][lane];
        }
        float bv0 = bias_v[b * Cn + l15];
        float bv1 = bias_v[b * Cn + l15 + 16];
        float csa0 = 0.f, csa1 = 0.f;
#pragma unroll
        for (int r = 0; r < 4; ++r) {
            int lrow = l0 + lg * 4 + r;
            size_t boff = ((size_t)b * Ln + lrow) * Cn;
            float d0 = acc0[r] + bv0, d1 = acc1[r] + bv1;
            if (!first) { d0 += b_ij[boff + l15]; d1 += b_ij[boff + l15 + 16]; }
            if (!last) {
                b_ij[boff + l15] = d0;
                b_ij[boff + l15 + 16] = d1;
            }
            float m = fmaxf(d0, d1);
            m = fmaxf(m, __shfl_xor(m, 1, 64)); m = fmaxf(m, __shfl_xor(m, 2, 64));
            m = fmaxf(m, __shfl_xor(m, 4, 64)); m = fmaxf(m, __shfl_xor(m, 8, 64));
            float e0 = __expf(d0 - m), e1 = __expf(d1 - m);
            float sm = e0 + e1;
            sm += __shfl_xor(sm, 1, 64); sm += __shfl_xor(sm, 2, 64);
            sm += __shfl_xor(sm, 4, 64); sm += __shfl_xor(sm, 8, 64);
            float inv = 1.0f / sm;
            float cw0 = e0 * inv, cw1 = e1 * inv;
            csa0 += cw0; csa1 += cw1;
            int ll = lgrp * 16 + lg * 4 + r;
            cw_sh[l15 * 40 + ll] = (short)f2bf(cw0);
            cw_sh[(l15 + 16) * 40 + ll] = (short)f2bf(cw1);
        }
        csa0 += __shfl_xor(csa0, 16, 64); csa0 += __shfl_xor(csa0, 32, 64);
        csa1 += __shfl_xor(csa1, 16, 64); csa1 += __shfl_xor(csa1, 32, 64);
        if (lg == 0) { cs_sh[lgrp][l15] = csa0; cs_sh[lgrp][l15 + 16] = csa1; }
    }
    __syncthreads();
    if (t < Cn) {
        float s = cs_sh[0][t] + cs_sh[1][t];
        csum_p[((size_t)lt2 * Bn + b) * Cn + t] = s;
    }
    if (t < 128) {
        int cc = t >> 2, slot = t & 3;
        bf16x8 vv;
#pragma unroll
        for (int j = 0; j < 8; ++j) vv[j] = cw_sh[cc * 40 + slot * 8 + j];
        *(bf16x8*)(c_wT + ((size_t)b * Cn + cc) * Ln + lt2 * 32 + slot * 8) = vv;
    }
}

// ----------------------------------------- x_cb[c][b][d] = c_w^T @ in -------
// grid (8 dt, 64 b), 256 thr / 4 waves. T14 async-stage pipeline; LDS
// [128 d][36 u32] l-pair pack, XOR-chunk swizzle. (R13-proven form.)
__global__ __launch_bounds__(256) void k_xc_m(const short* __restrict__ in_bf,
                                              const short* __restrict__ c_wT,
                                              short* __restrict__ x_cb) {
    __shared__ unsigned tile[128 * 36];   // 18432 B
    int dt = blockIdx.x, b = blockIdx.y;
    int t = threadIdx.x, w = t >> 6, lane = t & 63;
    int l15 = lane & 15, lg = lane >> 4;
    f32x4 acc[2][2];
#pragma unroll
    for (int h = 0; h < 2; ++h)
#pragma unroll
        for (int dd = 0; dd < 2; ++dd) acc[h][dd] = {0.f, 0.f, 0.f, 0.f};
    const short* A = c_wT + (size_t)b * Cn * Ln;   // [c][l]

    int oct = t & 15, lpA = t >> 4, lpB = lpA + 16;
    const short* gbase = in_bf + (size_t)b * Ln * Dn + dt * 128 + oct * 8;
    int colA = lpA ^ ((oct & 7) << 2);
    int colB = lpB ^ ((oct & 7) << 2);
    unsigned* trow = &tile[(oct * 8) * 36];

    bf16x8 ra0, ra1, rb0, rb1;
    bf16x8 a0c[2], a1c[2], a0n[2], a1n[2];

#define XC_LOADG(LC)                                                          \
    {                                                                         \
        const short* sA = gbase + (size_t)((LC) * 64 + 2 * lpA) * Dn;         \
        const short* sB = gbase + (size_t)((LC) * 64 + 2 * lpB) * Dn;         \
        ra0 = *(const bf16x8*)sA; ra1 = *(const bf16x8*)(sA + Dn);            \
        rb0 = *(const bf16x8*)sB; rb1 = *(const bf16x8*)(sB + Dn);            \
    }
#define XC_LOADA(LC, D0, D1)                                                  \
    _Pragma("unroll")                                                         \
    for (int ks = 0; ks < 2; ++ks) {                                          \
        int off = (LC) * 64 + ks * 32 + lg * 8;                               \
        D0[ks] = *(const bf16x8*)(A + (size_t)l15 * Ln + off);                \
        D1[ks] = *(const bf16x8*)(A + (size_t)(l15 + 16) * Ln + off);         \
    }

    XC_LOADG(0);
    XC_LOADA(0, a0c, a1c);

    for (int lc = 0; lc < 8; ++lc) {
#pragma unroll
        for (int k = 0; k < 8; ++k) {
            trow[k * 36 + colA] = (unsigned)(unsigned short)ra0[k] |
                                  ((unsigned)(unsigned short)ra1[k] << 16);
            trow[k * 36 + colB] = (unsigned)(unsigned short)rb0[k] |
                                  ((unsigned)(unsigned short)rb1[k] << 16);
        }
        __syncthreads();
        if (lc < 7) {
            XC_LOADG(lc + 1);
            XC_LOADA(lc + 1, a0n, a1n);
        }
#pragma unroll
        for (int ks = 0; ks < 2; ++ks) {
            int q = ks * 4 + lg;
#pragma unroll
            for (int dd = 0; dd < 2; ++dd) {
                int dloc = w * 32 + dd * 16 + l15;
                int qs = q ^ ((dloc >> 3) & 7);
                bf16x8 bb = *(const bf16x8*)&tile[dloc * 36 + qs * 4];
                acc[0][dd] = __builtin_amdgcn_mfma_f32_16x16x32_bf16(a0c[ks], bb, acc[0][dd], 0, 0, 0);
                acc[1][dd] = __builtin_amdgcn_mfma_f32_16x16x32_bf16(a1c[ks], bb, acc[1][dd], 0, 0, 0);
            }
        }
        __syncthreads();
        if (lc < 7) {
#pragma unroll
            for (int ks = 0; ks < 2; ++ks) { a0c[ks] = a0n[ks]; a1c[ks] = a1n[ks]; }
        }
    }
#undef XC_LOADG
#undef XC_LOADA
#pragma unroll
    for (int h = 0; h < 2; ++h)
#pragma unroll
        for (int dd = 0; dd < 2; ++dd)
#pragma unroll
            for (int r = 0; r < 4; ++r) {
                int c = 16 * h + lg * 4 + r;
                int d = dt * 128 + w * 32 + dd * 16 + l15;
                x_cb[((size_t)c * Bn + b) * Dn + d] = (short)f2bf(acc[h][dd][r]);
            }
}

// ---------------------------------------------------------------------------
extern "C" void kernel_launch(void* const* d_in, const int* in_sizes, int n_in,
                              void* d_out, int out_size, void* d_ws, size_t ws_size,
                              hipStream_t stream) {
    const float* in   = (const float*)d_in[0];
    const float* fc_w = (const float*)d_in[1];
    const float* fc_b = (const float*)d_in[2];
    float* out = (float*)d_out;

    char* p = (char*)d_ws;
    auto alloc = [&](size_t bytes) -> char* {
        char* r = p;
        p += (bytes + 255) & ~(size_t)255;
        return r;
    };
    short* in_bf  = (short*)alloc((size_t)Bn * Ln * Dn * 2);   // 64 MB
    short* fc_wT  = (short*)alloc((size_t)COn * Dn * 2);       // 4 MB
    short* fc_wb  = (short*)alloc((size_t)COn * Dn * 2);       // 4 MB
    short* w_vb   = (short*)alloc((size_t)Bn * Cn * Dn * 2);   // 4 MB
    short* c_wT   = (short*)alloc((size_t)Bn * Cn * Ln * 2);   // 2 MB
    short* x_cb   = (short*)alloc((size_t)Cn * Bn * Dn * 2);   // 4 MB
    short* v_bf   = (short*)alloc((size_t)Bn * Cn * On * 2);   // 256 KB
    float* rs_p   = (float*)alloc((size_t)Bn * 16 * Dn * 4);   // 4 MB
    unsigned short* rs_bf = (unsigned short*)alloc((size_t)Bn * Dn * 2);
    float* b_ij   = (float*)alloc((size_t)Bn * Ln * Cn * 4);   // 4 MB
    float* bias_v = (float*)alloc((size_t)Bn * Cn * 4);
    float* csum_p = (float*)alloc((size_t)16 * Bn * Cn * 4);

    k_ctr<<<dim3(16, Bn), 256, 0, stream>>>(in, in_bf, rs_p);
    k_prep2<<<384, 256, 0, stream>>>(fc_w, fc_wT, fc_wb, rs_p, rs_bf);
    k_sv3<<<dim3(4, Cn), 64, 0, stream>>>((const short*)rs_bf, csum_p, fc_wT,
                                          fc_b, v_bf, nullptr, bias_v, 1);
    for (int it = 1; it <= 2; ++it) {
        k_wv_m<<<dim3(4, Cn), 256, 0, stream>>>(fc_wb, v_bf, w_vb);
        k_route2<<<dim3(16, Bn), 256, 0, stream>>>(in_bf, w_vb, bias_v, b_ij,
                                                   c_wT, csum_p,
                                                   (it == 1) ? 1 : 0,
                                                   (it == 2) ? 1 : 0);
        k_xc_m<<<dim3(8, Bn), 256, 0, stream>>>(in_bf, c_wT, x_cb);
        k_sv3<<<dim3(4, Cn), 64, 0, stream>>>(x_cb, csum_p, fc_wT, fc_b,
                                              v_bf, (it == 2) ? out : nullptr,
                                              bias_v, 0);
    }
}

// Round 17
// 171.876 us; speedup vs baseline: 1.0767x; 1.0311x over previous
//
#include <hip/hip_runtime.h>

// CapsuleLayer: B=64, L=512, D=1024, C=32, O=64, 3 routing iters.
// u_hat never materialized:
//   dots[b,l,c] = in[b,l,:]@w_v[b,c,:] + bias_v[b,c]   (w_v[b,c,d] = sum_o fc_w[d,cO+o] v[b,c,o])
//   s_j[b,c,:]  = x_c[b,c,:]@fc_w[:,c,:] + csum[b,c]*fc_b[c,:]   (x_c = sum_l c_w * in)
// All contractions via mfma_f32_16x16x32_bf16. Single bf16 input copy
// in_bf[b][l][d]. k_ctr: fully-sequential streaming (R13-proven; NT-load
// variant was neutral-to-negative, reverted). k_route2: K split across
// wave pairs (LDS-reduced) -> 4 waves/SIMD. k_xc_m: 128-d tiles, LDS
// l-pair transpose staging + T14 async-stage pipeline. Final k_sv3 skips
// dead v_bf/bias_v stores.

namespace {
constexpr int Bn = 64, Ln = 512, Dn = 1024, Cn = 32, On = 64, COn = Cn * On;
}

typedef float f32x4 __attribute__((ext_vector_type(4)));
typedef short bf16x8 __attribute__((ext_vector_type(8)));

static __device__ __forceinline__ unsigned f2bf(float f) {
    unsigned u = __float_as_uint(f);
    u += 0x7fff + ((u >> 16) & 1);   // RNE
    return u >> 16;
}

// ------------------------------------------------------------ conv ----------
// grid (16 lc, 64 b): block streams 32 complete rows (128 KB contiguous).
// Wave w covers d in [w*256, w*256+256); lane owns one float4 column.
__global__ __launch_bounds__(256) void k_ctr(const float* __restrict__ in,
                                             short* __restrict__ in_bf,
                                             float* __restrict__ rs_p) {
    int lc = blockIdx.x, b = blockIdx.y;
    int t = threadIdx.x, w = t >> 6, lane = t & 63;
    int l0 = lc * 32;
    int d0 = w * 256 + lane * 4;
    const float* src = in + ((size_t)b * Ln + l0) * Dn + d0;
    short* dst = in_bf + ((size_t)b * Ln + l0) * Dn + d0;
    float4 s4 = make_float4(0.f, 0.f, 0.f, 0.f);
#pragma unroll 8
    for (int r = 0; r < 32; ++r) {
        float4 x = *(const float4*)(src + (size_t)r * Dn);
        s4.x += x.x; s4.y += x.y; s4.z += x.z; s4.w += x.w;
        unsigned lo = f2bf(x.x) | (f2bf(x.y) << 16);
        unsigned hi = f2bf(x.z) | (f2bf(x.w) << 16);
        *(uint2*)(dst + (size_t)r * Dn) = make_uint2(lo, hi);
    }
    *(float4*)(rs_p + ((size_t)b * 16 + lc) * Dn + d0) = s4;
}

// -------------------------------------------------------- wprep + rsred -----
// blocks [0,128): fc_w fp32 [d][co] -> fc_wT bf16 [co][d] + fc_wb bf16 [d][co]
// blocks [128,384): rsred — rs_p partials (16) -> rs_bf (/32, bf16)
__global__ __launch_bounds__(256) void k_prep2(const float* __restrict__ fc_w,
                                               short* __restrict__ fc_wT,
                                               short* __restrict__ fc_wb,
                                               const float* __restrict__ rs_p,
                                               unsigned short* __restrict__ rs_bf) {
    __shared__ short tr[64 * 260];      // used by wprep blocks only
    int t = threadIdx.x;
    if (blockIdx.x < 128) {
        int id = blockIdx.x;
        int d0 = (id & 15) * 64;
        int co0 = (id >> 4) * 256;
        int grp = t >> 6, cq = t & 63;
#pragma unroll
        for (int i = 0; i < 16; ++i) {
            int row = grp + 4 * i;
            float4 x = *(const float4*)(fc_w + (size_t)(d0 + row) * COn + co0 + cq * 4);
            short4 s4 = make_short4((short)f2bf(x.x), (short)f2bf(x.y),
                                    (short)f2bf(x.z), (short)f2bf(x.w));
            *(short4*)(&tr[row * 260 + cq * 4]) = s4;
            *(short4*)(fc_wb + (size_t)(d0 + row) * COn + co0 + cq * 4) = s4;
        }
        __syncthreads();
#pragma unroll
        for (int i = 0; i < 8; ++i) {
            int idx = t + 256 * i;
            int corow = idx >> 3, slot = idx & 7;
            bf16x8 v;
#pragma unroll
            for (int j = 0; j < 8; ++j) v[j] = tr[(slot * 8 + j) * 260 + corow];
            *(bf16x8*)(fc_wT + (size_t)(co0 + corow) * Dn + d0 + slot * 8) = v;
        }
    } else {
        int id = blockIdx.x - 128;      // 0..255
        int b = id >> 2, dq = id & 3;
        int d = dq * 256 + t;
        float s = 0.f;
#pragma unroll
        for (int lc = 0; lc < 16; ++lc) s += rs_p[((size_t)b * 16 + lc) * Dn + d];
        rs_bf[b * Dn + d] = (unsigned short)f2bf(s * (1.0f / 32.0f));
    }
}

// ------------------------------------------------------- s -> squash -> v ---
// Per-(btile,c) MFMA GEMM: one wave computes S[16 b][64 o]. Grid (4, 32).
// When fout != nullptr (final iter), v_bf/bias_v stores are dead -> skipped.
__global__ __launch_bounds__(64) void k_sv3(const short* __restrict__ xA,
                                            const float* __restrict__ csum_p,
                                            const short* __restrict__ fc_wT,
                                            const float* __restrict__ fc_b,
                                            short* __restrict__ v_bf,
                                            float* __restrict__ fout,
                                            float* __restrict__ bias_v,
                                            int mode0) {
    int w = blockIdx.x;                 // b-tile 0..3
    int c = blockIdx.y;
    int lane = threadIdx.x;             // 0..63
    int l15 = lane & 15, lg = lane >> 4;
    const short* A = mode0 ? xA : (xA + (size_t)c * Bn * Dn);   // [b][d]
    const short* Bw = fc_wT + (size_t)c * On * Dn;              // [o][d]
    f32x4 acc[4];
#pragma unroll
    for (int i = 0; i < 4; ++i) acc[i] = {0.f, 0.f, 0.f, 0.f};
#pragma unroll 4
    for (int ks = 0; ks < 32; ++ks) {
        int koff = ks * 32 + lg * 8;
        bf16x8 a = *(const bf16x8*)(A + (size_t)(w * 16 + l15) * Dn + koff);
#pragma unroll
        for (int dt = 0; dt < 4; ++dt) {
            bf16x8 bbf = *(const bf16x8*)(Bw + (size_t)(dt * 16 + l15) * Dn + koff);
            acc[dt] = __builtin_amdgcn_mfma_f32_16x16x32_bf16(a, bbf, acc[dt], 0, 0, 0);
        }
    }
    float fb[4];
#pragma unroll
    for (int dt = 0; dt < 4; ++dt) fb[dt] = fc_b[c * On + dt * 16 + l15];
#pragma unroll
    for (int r = 0; r < 4; ++r) {
        int brow = w * 16 + lg * 4 + r;
        float cs;
        if (mode0) {
            cs = 16.0f;
        } else {
            cs = 0.f;
#pragma unroll
            for (int lt = 0; lt < 16; ++lt) cs += csum_p[((size_t)lt * Bn + brow) * Cn + c];
        }
        float s0 = acc[0][r] + cs * fb[0];
        float s1 = acc[1][r] + cs * fb[1];
        float s2 = acc[2][r] + cs * fb[2];
        float s3 = acc[3][r] + cs * fb[3];
        float sq = s0 * s0 + s1 * s1 + s2 * s2 + s3 * s3;
        sq += __shfl_xor(sq, 1, 64); sq += __shfl_xor(sq, 2, 64);
        sq += __shfl_xor(sq, 4, 64); sq += __shfl_xor(sq, 8, 64);
        float scale = sq / (1.0f + sq) * rsqrtf(sq + 1e-8f);
        float v0 = scale * s0, v1 = scale * s1, v2 = scale * s2, v3 = scale * s3;
        size_t vo = ((size_t)brow * Cn + c) * On;
        if (fout) {
            fout[vo + 0 * 16 + l15] = v0;
            fout[vo + 1 * 16 + l15] = v1;
            fout[vo + 2 * 16 + l15] = v2;
            fout[vo + 3 * 16 + l15] = v3;
        } else {
            v_bf[vo + 0 * 16 + l15] = (short)f2bf(v0);
            v_bf[vo + 1 * 16 + l15] = (short)f2bf(v1);
            v_bf[vo + 2 * 16 + l15] = (short)f2bf(v2);
            v_bf[vo + 3 * 16 + l15] = (short)f2bf(v3);
            float bv = fb[0] * v0 + fb[1] * v1 + fb[2] * v2 + fb[3] * v3;
            bv += __shfl_xor(bv, 1, 64); bv += __shfl_xor(bv, 2, 64);
            bv += __shfl_xor(bv, 4, 64); bv += __shfl_xor(bv, 8, 64);
            if (l15 == 0) bias_v[brow * Cn + c] = bv;
        }
    }
}

// ------------------------------------------- w_v via MFMA (contract o=64) ---
// grid (4 dslab, 32 c), 256 thr / 4 waves; wave: 64 d x 64 b, K=64.
__global__ __launch_bounds__(256) void k_wv_m(const short* __restrict__ fc_wb,
                                              const short* __restrict__ v_bf,
                                              short* __restrict__ w_vb) {
    int dsl = blockIdx.x, c = blockIdx.y;
    int t = threadIdx.x, w = t >> 6, lane = t & 63;
    int l15 = lane & 15, lg = lane >> 4;
    int dbase = dsl * 256 + w * 64;
    f32x4 acc[4][4];
#pragma unroll
    for (int i = 0; i < 4; ++i)
#pragma unroll
        for (int j = 0; j < 4; ++j) acc[i][j] = {0.f, 0.f, 0.f, 0.f};
#pragma unroll
    for (int ks = 0; ks < 2; ++ks) {
        int o = ks * 32 + lg * 8;
        bf16x8 bfr[4];
#pragma unroll
        for (int nt = 0; nt < 4; ++nt)
            bfr[nt] = *(const bf16x8*)(v_bf + ((size_t)(nt * 16 + l15) * Cn + c) * On + o);
#pragma unroll
        for (int mt = 0; mt < 4; ++mt) {
            bf16x8 a = *(const bf16x8*)(fc_wb + (size_t)(dbase + mt * 16 + l15) * COn + c * On + o);
#pragma unroll
            for (int nt = 0; nt < 4; ++nt)
                acc[mt][nt] = __builtin_amdgcn_mfma_f32_16x16x32_bf16(a, bfr[nt], acc[mt][nt], 0, 0, 0);
        }
    }
#pragma unroll
    for (int mt = 0; mt < 4; ++mt)
#pragma unroll
        for (int nt = 0; nt < 4; ++nt) {
            int bb = nt * 16 + l15;
            int d = dbase + mt * 16 + lg * 4;
            *(short4*)(w_vb + ((size_t)bb * Cn + c) * Dn + d) =
                make_short4((short)f2bf(acc[mt][nt][0]), (short)f2bf(acc[mt][nt][1]),
                            (short)f2bf(acc[mt][nt][2]), (short)f2bf(acc[mt][nt][3]));
        }
}

// ------------------------------- dots -> b_ij update -> softmax -> c_wT -----
// K-split: grid (16 lt2, 64 b), 4 waves = 2 l-groups x 2 K-halves. Each wave
// does K=512; partners LDS-reduce. 1024 blocks -> 4 waves/SIMD.
__global__ __launch_bounds__(256) void k_route2(const short* __restrict__ in_bf,
                                                const short* __restrict__ w_v,
                                                const float* __restrict__ bias_v,
                                                float* __restrict__ b_ij,
                                                short* __restrict__ c_wT,
                                                float* __restrict__ csum_p,
                                                int first, int last) {
    __shared__ float red[2][8][64];     // [lgrp][acc j][lane]
    __shared__ short cw_sh[Cn * 40];    // [c][32 l + pad]
    __shared__ float cs_sh[2][Cn];
    int lt2 = blockIdx.x, b = blockIdx.y;
    int t = threadIdx.x, w = t >> 6, lane = t & 63;
    int lgrp = w >> 1, kh = w & 1;
    int l15 = lane & 15, lg = lane >> 4;
    int l0 = lt2 * 32 + lgrp * 16;
    f32x4 acc0 = {0.f, 0.f, 0.f, 0.f}, acc1 = {0.f, 0.f, 0.f, 0.f};
    const short* Ap = in_bf + ((size_t)b * Ln + l0 + l15) * Dn + kh * 512;
    const short* Bp = w_v + (size_t)b * Cn * Dn + kh * 512;
#pragma unroll 4
    for (int ks = 0; ks < 16; ++ks) {
        int koff = ks * 32 + lg * 8;
        bf16x8 a = *(const bf16x8*)(Ap + koff);
        bf16x8 b0 = *(const bf16x8*)(Bp + (size_t)l15 * Dn + koff);
        bf16x8 b1 = *(const bf16x8*)(Bp + (size_t)(l15 + 16) * Dn + koff);
        acc0 = __builtin_amdgcn_mfma_f32_16x16x32_bf16(a, b0, acc0, 0, 0, 0);
        acc1 = __builtin_amdgcn_mfma_f32_16x16x32_bf16(a, b1, acc1, 0, 0, 0);
    }
    if (kh == 1) {
#pragma unroll
        for (int j = 0; j < 4; ++j) {
            red[lgrp][j][lane] = acc0[j];
            red[lgrp][4 + j][lane] = acc1[j];
        }
    }
    __syncthreads();
    if (kh == 0) {
#pragma unroll
        for (int j = 0; j < 4; ++j) {
            acc0[j] += red[lgrp][j][lane];
            acc1[j] += red[lgrp][4 + j][lane];
        }
        float bv0 = bias_v[b * Cn + l15];
        float bv1 = bias_v[b * Cn + l15 + 16];
        float csa0 = 0.f, csa1 = 0.f;
#pragma unroll
        for (int r = 0; r < 4; ++r) {
            int lrow = l0 + lg * 4 + r;
            size_t boff = ((size_t)b * Ln + lrow) * Cn;
            float d0 = acc0[r] + bv0, d1 = acc1[r] + bv1;
            if (!first) { d0 += b_ij[boff + l15]; d1 += b_ij[boff + l15 + 16]; }
            if (!last) {
                b_ij[boff + l15] = d0;
                b_ij[boff + l15 + 16] = d1;
            }
            float m = fmaxf(d0, d1);
            m = fmaxf(m, __shfl_xor(m, 1, 64)); m = fmaxf(m, __shfl_xor(m, 2, 64));
            m = fmaxf(m, __shfl_xor(m, 4, 64)); m = fmaxf(m, __shfl_xor(m, 8, 64));
            float e0 = __expf(d0 - m), e1 = __expf(d1 - m);
            float sm = e0 + e1;
            sm += __shfl_xor(sm, 1, 64); sm += __shfl_xor(sm, 2, 64);
            sm += __shfl_xor(sm, 4, 64); sm += __shfl_xor(sm, 8, 64);
            float inv = 1.0f / sm;
            float cw0 = e0 * inv, cw1 = e1 * inv;
            csa0 += cw0; csa1 += cw1;
            int ll = lgrp * 16 + lg * 4 + r;
            cw_sh[l15 * 40 + ll] = (short)f2bf(cw0);
            cw_sh[(l15 + 16) * 40 + ll] = (short)f2bf(cw1);
        }
        csa0 += __shfl_xor(csa0, 16, 64); csa0 += __shfl_xor(csa0, 32, 64);
        csa1 += __shfl_xor(csa1, 16, 64); csa1 += __shfl_xor(csa1, 32, 64);
        if (lg == 0) { cs_sh[lgrp][l15] = csa0; cs_sh[lgrp][l15 + 16] = csa1; }
    }
    __syncthreads();
    if (t < Cn) {
        float s = cs_sh[0][t] + cs_sh[1][t];
        csum_p[((size_t)lt2 * Bn + b) * Cn + t] = s;
    }
    if (t < 128) {
        int cc = t >> 2, slot = t & 3;
        bf16x8 vv;
#pragma unroll
        for (int j = 0; j < 8; ++j) vv[j] = cw_sh[cc * 40 + slot * 8 + j];
        *(bf16x8*)(c_wT + ((size_t)b * Cn + cc) * Ln + lt2 * 32 + slot * 8) = vv;
    }
}

// ----------------------------------------- x_cb[c][b][d] = c_w^T @ in -------
// grid (8 dt, 64 b), 256 thr / 4 waves. T14 async-stage pipeline; LDS
// [128 d][36 u32] l-pair pack, XOR-chunk swizzle. (R13-proven form.)
__global__ __launch_bounds__(256) void k_xc_m(const short* __restrict__ in_bf,
                                              const short* __restrict__ c_wT,
                                              short* __restrict__ x_cb) {
    __shared__ unsigned tile[128 * 36];   // 18432 B
    int dt = blockIdx.x, b = blockIdx.y;
    int t = threadIdx.x, w = t >> 6, lane = t & 63;
    int l15 = lane & 15, lg = lane >> 4;
    f32x4 acc[2][2];
#pragma unroll
    for (int h = 0; h < 2; ++h)
#pragma unroll
        for (int dd = 0; dd < 2; ++dd) acc[h][dd] = {0.f, 0.f, 0.f, 0.f};
    const short* A = c_wT + (size_t)b * Cn * Ln;   // [c][l]

    int oct = t & 15, lpA = t >> 4, lpB = lpA + 16;
    const short* gbase = in_bf + (size_t)b * Ln * Dn + dt * 128 + oct * 8;
    int colA = lpA ^ ((oct & 7) << 2);
    int colB = lpB ^ ((oct & 7) << 2);
    unsigned* trow = &tile[(oct * 8) * 36];

    bf16x8 ra0, ra1, rb0, rb1;
    bf16x8 a0c[2], a1c[2], a0n[2], a1n[2];

#define XC_LOADG(LC)                                                          \
    {                                                                         \
        const short* sA = gbase + (size_t)((LC) * 64 + 2 * lpA) * Dn;         \
        const short* sB = gbase + (size_t)((LC) * 64 + 2 * lpB) * Dn;         \
        ra0 = *(const bf16x8*)sA; ra1 = *(const bf16x8*)(sA + Dn);            \
        rb0 = *(const bf16x8*)sB; rb1 = *(const bf16x8*)(sB + Dn);            \
    }
#define XC_LOADA(LC, D0, D1)                                                  \
    _Pragma("unroll")                                                         \
    for (int ks = 0; ks < 2; ++ks) {                                          \
        int off = (LC) * 64 + ks * 32 + lg * 8;                               \
        D0[ks] = *(const bf16x8*)(A + (size_t)l15 * Ln + off);                \
        D1[ks] = *(const bf16x8*)(A + (size_t)(l15 + 16) * Ln + off);         \
    }

    XC_LOADG(0);
    XC_LOADA(0, a0c, a1c);

    for (int lc = 0; lc < 8; ++lc) {
#pragma unroll
        for (int k = 0; k < 8; ++k) {
            trow[k * 36 + colA] = (unsigned)(unsigned short)ra0[k] |
                                  ((unsigned)(unsigned short)ra1[k] << 16);
            trow[k * 36 + colB] = (unsigned)(unsigned short)rb0[k] |
                                  ((unsigned)(unsigned short)rb1[k] << 16);
        }
        __syncthreads();
        if (lc < 7) {
            XC_LOADG(lc + 1);
            XC_LOADA(lc + 1, a0n, a1n);
        }
#pragma unroll
        for (int ks = 0; ks < 2; ++ks) {
            int q = ks * 4 + lg;
#pragma unroll
            for (int dd = 0; dd < 2; ++dd) {
                int dloc = w * 32 + dd * 16 + l15;
                int qs = q ^ ((dloc >> 3) & 7);
                bf16x8 bb = *(const bf16x8*)&tile[dloc * 36 + qs * 4];
                acc[0][dd] = __builtin_amdgcn_mfma_f32_16x16x32_bf16(a0c[ks], bb, acc[0][dd], 0, 0, 0);
                acc[1][dd] = __builtin_amdgcn_mfma_f32_16x16x32_bf16(a1c[ks], bb, acc[1][dd], 0, 0, 0);
            }
        }
        __syncthreads();
        if (lc < 7) {
#pragma unroll
            for (int ks = 0; ks < 2; ++ks) { a0c[ks] = a0n[ks]; a1c[ks] = a1n[ks]; }
        }
    }
#undef XC_LOADG
#undef XC_LOADA
#pragma unroll
    for (int h = 0; h < 2; ++h)
#pragma unroll
        for (int dd = 0; dd < 2; ++dd)
#pragma unroll
            for (int r = 0; r < 4; ++r) {
                int c = 16 * h + lg * 4 + r;
                int d = dt * 128 + w * 32 + dd * 16 + l15;
                x_cb[((size_t)c * Bn + b) * Dn + d] = (short)f2bf(acc[h][dd][r]);
            }
}

// ---------------------------------------------------------------------------
extern "C" void kernel_launch(void* const* d_in, const int* in_sizes, int n_in,
                              void* d_out, int out_size, void* d_ws, size_t ws_size,
                              hipStream_t stream) {
    const float* in   = (const float*)d_in[0];
    const float* fc_w = (const float*)d_in[1];
    const float* fc_b = (const float*)d_in[2];
    float* out = (float*)d_out;

    char* p = (char*)d_ws;
    auto alloc = [&](size_t bytes) -> char* {
        char* r = p;
        p += (bytes + 255) & ~(size_t)255;
        return r;
    };
    short* in_bf  = (short*)alloc((size_t)Bn * Ln * Dn * 2);   // 64 MB
    short* fc_wT  = (short*)alloc((size_t)COn * Dn * 2);       // 4 MB
    short* fc_wb  = (short*)alloc((size_t)COn * Dn * 2);       // 4 MB
    short* w_vb   = (short*)alloc((size_t)Bn * Cn * Dn * 2);   // 4 MB
    short* c_wT   = (short*)alloc((size_t)Bn * Cn * Ln * 2);   // 2 MB
    short* x_cb   = (short*)alloc((size_t)Cn * Bn * Dn * 2);   // 4 MB
    short* v_bf   = (short*)alloc((size_t)Bn * Cn * On * 2);   // 256 KB
    float* rs_p   = (float*)alloc((size_t)Bn * 16 * Dn * 4);   // 4 MB
    unsigned short* rs_bf = (unsigned short*)alloc((size_t)Bn * Dn * 2);
    float* b_ij   = (float*)alloc((size_t)Bn * Ln * Cn * 4);   // 4 MB
    float* bias_v = (float*)alloc((size_t)Bn * Cn * 4);
    float* csum_p = (float*)alloc((size_t)16 * Bn * Cn * 4);

    k_ctr<<<dim3(16, Bn), 256, 0, stream>>>(in, in_bf, rs_p);
    k_prep2<<<384, 256, 0, stream>>>(fc_w, fc_wT, fc_wb, rs_p, rs_bf);
    k_sv3<<<dim3(4, Cn), 64, 0, stream>>>((const short*)rs_bf, csum_p, fc_wT,
                                          fc_b, v_bf, nullptr, bias_v, 1);
    for (int it = 1; it <= 2; ++it) {
        k_wv_m<<<dim3(4, Cn), 256, 0, stream>>>(fc_wb, v_bf, w_vb);
        k_route2<<<dim3(16, Bn), 256, 0, stream>>>(in_bf, w_vb, bias_v, b_ij,
                                                   c_wT, csum_p,
                                                   (it == 1) ? 1 : 0,
                                                   (it == 2) ? 1 : 0);
        k_xc_m<<<dim3(8, Bn), 256, 0, stream>>>(in_bf, c_wT, x_cb);
        k_sv3<<<dim3(4, Cn), 64, 0, stream>>>(x_cb, csum_p, fc_wT, fc_b,
                                              v_bf, (it == 2) ? out : nullptr,
                                              bias_v, 0);
    }
}